// Round 1
// baseline (12323.771 us; speedup 1.0000x reference)
//
#include <hip/hip_runtime.h>
#include <cstdint>
#include <cstddef>

// Bidirectional 3-layer tanh RNN, S=512 B=512 D=300 H=256.
// Structure: 192 persistent blocks = 2 dirs x 3 layers x 32 batch-tiles (16 rows each).
// Layer pipeline over global ring buffers with agent-scope atomic flags.
// GEMM: fp16 2-term split (A_hi@W_hi + A_lo@W_hi) on mfma_f32_16x16x32_f16, fp32 acc.
// Weights pre-permuted into MFMA lane-chunks by prep kernel (1KB coalesced loads).

#define SEQ    512
#define BATCH  512
#define DIN    300
#define HDIM   256
#define NT     512   // threads per main block (8 waves)

typedef _Float16 f16x8 __attribute__((ext_vector_type(8)));
typedef float    f32x4 __attribute__((ext_vector_type(4)));

// ---- workspace layout (bytes) ----
// weights, fp16 lane-chunked, per dir: l0 = 16*18*64*8*2 = 294912, l1/l2 = 16*16*64*8*2 = 262144
#define WD_STRIDE 819200
#define W_L1_OFF  294912
#define W_L2_OFF  557056
#define HOFF      1638400                 // u32 hbuf [2 dir][2 layer][4 ring][512 row][256 col]
#define FOFF      (HOFF + 8388608)        // prodf u32[128], then consf u32[128]

static __device__ __forceinline__ uint16_t f16bits(_Float16 h) {
    union { _Float16 h; uint16_t u; } v; v.h = h; return v.u;
}

// ---------------- prep: permute/convert weights to fp16 lane-chunks, zero flags -------------
__global__ void rnn_prep(const float* __restrict__ fW_ih0, const float* __restrict__ fW_ih,
                         const float* __restrict__ fW_hh,  const float* __restrict__ bW_ih0,
                         const float* __restrict__ bW_ih,  const float* __restrict__ bW_hh,
                         uint8_t* __restrict__ ws)
{
    if (blockIdx.x == 400) {            // zero flags (prodf 128 + consf 128)
        ((uint32_t*)(ws + FOFF))[threadIdx.x] = 0;
        return;
    }
    const int gid = blockIdx.x * 256 + threadIdx.x;   // 0..102399, one 16B chunk-row each
    const int d = gid / 51200;
    int r = gid - d * 51200;
    const float* Wih0 = d ? bW_ih0 : fW_ih0;
    const float* Wih  = d ? bW_ih  : fW_ih;
    const float* Whh  = d ? bW_hh  : fW_hh;
    int l, lr, Ktiles; size_t base;
    if (r < 18432)      { l = 0; lr = r;         Ktiles = 18; base = (size_t)d*WD_STRIDE; }
    else if (r < 34816) { l = 1; lr = r - 18432; Ktiles = 16; base = (size_t)d*WD_STRIDE + W_L1_OFF; }
    else                { l = 2; lr = r - 34816; Ktiles = 16; base = (size_t)d*WD_STRIDE + W_L2_OFF; }
    const int ck = lr >> 6, lane = lr & 63;
    const int wc = ck / Ktiles, kt = ck - wc * Ktiles;
    const int col = wc * 16 + (lane & 15);
    const int k0  = kt * 32 + (lane >> 4) * 8;
    _Float16 vals[8];
    #pragma unroll
    for (int e = 0; e < 8; ++e) {
        const int k = k0 + e;
        float v = 0.f;
        if (l == 0) {
            if (k < 300)      v = Wih0[k * 256 + col];
            else if (k < 556) v = Whh[(k - 300) * 256 + col];
        } else {
            if (k < 256) v = Wih[((l - 1) * 256 + k) * 256 + col];
            else         v = Whh[(l * 256 + (k - 256)) * 256 + col];
        }
        vals[e] = (_Float16)v;
    }
    *(f16x8*)(ws + base + ((size_t)ck * 64 + lane) * 16) = *(const f16x8*)vals;
}

// ---------------- main persistent RNN block ----------------
template<int L>
__device__ void run_block(const float* __restrict__ x, const float* __restrict__ bias_base,
                          uint8_t* __restrict__ ws, float* __restrict__ out,
                          int d, int i, uint16_t* Ahi, uint16_t* Alo, uint32_t* opack)
{
    constexpr int KT  = (L == 0) ? 18  : 16;     // K tiles of 32
    constexpr int KPS = (L == 0) ? 584 : 520;    // padded LDS row stride (elements)
    constexpr int K1  = (L == 0) ? 300 : 256;    // recurrent-region offset in K
    constexpr size_t WOFFL = (L == 0) ? 0 : ((L == 1) ? W_L1_OFF : W_L2_OFF);

    const int tid  = threadIdx.x;
    const int lane = tid & 63;
    const int w    = tid >> 6;                   // 8 waves; wave handles 2 coltiles (32 cols)

    const _Float16* __restrict__ Wreg = (const _Float16*)(ws + (size_t)d * WD_STRIDE + WOFFL);
    uint32_t* hbuf  = (uint32_t*)(ws + HOFF);
    uint32_t* prodf = (uint32_t*)(ws + FOFF);
    uint32_t* consf = prodf + 128;

    const int grow0 = i * 16;
    const float* bias = bias_base + L * HDIM;
    float bv[2];
    #pragma unroll
    for (int c = 0; c < 2; ++c) bv[c] = bias[(w * 2 + c) * 16 + (lane & 15)];

    for (int idx = tid; idx < 16 * KPS; idx += NT) { Ahi[idx] = 0; Alo[idx] = 0; }

    const uint16_t* ArH = Ahi + (lane & 15) * KPS + ((lane >> 4) << 3);
    const uint16_t* ArL = Alo + (lane & 15) * KPS + ((lane >> 4) << 3);
    const _Float16* Wlane = Wreg + lane * 8;

    const int upFlag = (d * 2 + (L - 1)) * 32 + i;   // used when L>0
    const int myFlag = (d * 2 + L) * 32 + i;         // used when L<2
    __syncthreads();

    for (int t = 0; t < SEQ; ++t) {
        // ---- waits (tid 0 only; others park at barrier) ----
        if (tid == 0) {
            if (L > 0) {
                const uint32_t tgt = (uint32_t)NT * (uint32_t)(t + 1);
                while (__hip_atomic_load(&prodf[upFlag], __ATOMIC_RELAXED, __HIP_MEMORY_SCOPE_AGENT) < tgt)
                    __builtin_amdgcn_s_sleep(2);
            }
            if (L < 2 && t >= 4) {
                const uint32_t tgt = (uint32_t)NT * (uint32_t)(t - 3);
                while (__hip_atomic_load(&consf[myFlag], __ATOMIC_RELAXED, __HIP_MEMORY_SCOPE_AGENT) < tgt)
                    __builtin_amdgcn_s_sleep(2);
            }
        }
        __syncthreads();   // A

        // ---- stage cross-layer input into k in [0, K1) ----
        if (L == 0) {
            const int ts = d ? (SEQ - 1 - t) : t;
            const float* xs = x + ((size_t)ts * BATCH + grow0) * DIN;
            for (int p = tid; p < 2400; p += NT) {
                const int r = p / 150, c2 = (p - r * 150) * 2;
                const float2 v = *(const float2*)(xs + r * DIN + c2);
                const _Float16 h0 = (_Float16)v.x, h1 = (_Float16)v.y;
                const _Float16 g0 = (_Float16)(v.x - (float)h0), g1 = (_Float16)(v.y - (float)h1);
                *(uint32_t*)&Ahi[r * KPS + c2] = (uint32_t)f16bits(h0) | ((uint32_t)f16bits(h1) << 16);
                *(uint32_t*)&Alo[r * KPS + c2] = (uint32_t)f16bits(g0) | ((uint32_t)f16bits(g1) << 16);
            }
        } else {
            const uint32_t* src = hbuf + ((size_t)((d * 2 + (L - 1)) * 4 + (t & 3)) * 512 + grow0) * 256;
            for (int e = tid; e < 4096; e += NT) {
                const uint32_t v = __hip_atomic_load(src + e, __ATOMIC_RELAXED, __HIP_MEMORY_SCOPE_AGENT);
                const int r = e >> 8, c = e & 255;
                Ahi[r * KPS + c] = (uint16_t)(v >> 16);
                Alo[r * KPS + c] = (uint16_t)(v & 0xffffu);
            }
            __hip_atomic_fetch_add(&consf[upFlag], 1u, __ATOMIC_RELAXED, __HIP_MEMORY_SCOPE_AGENT);
        }
        __syncthreads();   // B

        // ---- GEMM: z = A_hi @ W + A_lo @ W  (fp32 accum) ----
        f32x4 a0 = {0.f,0.f,0.f,0.f}, a1 = {0.f,0.f,0.f,0.f};
        {
            const int cb = (w * 2) * KT * 512;   // this wave's first chunk (elements)
            #pragma unroll
            for (int kt = 0; kt < KT; ++kt) {
                const f16x8 ah = *(const f16x8*)(ArH + kt * 32);
                const f16x8 al = *(const f16x8*)(ArL + kt * 32);
                const _Float16* bp = Wlane + cb + kt * 512;
                const f16x8 b0 = *(const f16x8*)(bp);
                const f16x8 b1 = *(const f16x8*)(bp + KT * 512);
                a0 = __builtin_amdgcn_mfma_f32_16x16x32_f16(ah, b0, a0, 0, 0, 0);
                a0 = __builtin_amdgcn_mfma_f32_16x16x32_f16(al, b0, a0, 0, 0, 0);
                a1 = __builtin_amdgcn_mfma_f32_16x16x32_f16(ah, b1, a1, 0, 0, 0);
                a1 = __builtin_amdgcn_mfma_f32_16x16x32_f16(al, b1, a1, 0, 0, 0);
            }
        }

        // ---- activation: h = tanh(z + b); pack hi/lo fp16 ----
        {
            const int r0 = (lane >> 4) << 2;     // C/D: col = lane&15, row = (lane>>4)*4 + j
            f32x4 acc[2] = { a0, a1 };
            #pragma unroll
            for (int c = 0; c < 2; ++c) {
                const int col = (w * 2 + c) * 16 + (lane & 15);
                #pragma unroll
                for (int j = 0; j < 4; ++j) {
                    float z = acc[c][j] + bv[c];
                    z = fminf(fmaxf(z, -15.f), 15.f);
                    const float ex = __expf(2.f * z);
                    const float hv = (ex - 1.f) / (ex + 1.f);
                    const _Float16 hh = (_Float16)hv;
                    const _Float16 hl = (_Float16)(hv - (float)hh);
                    opack[(r0 + j) * 256 + col] = ((uint32_t)f16bits(hh) << 16) | (uint32_t)f16bits(hl);
                    if (L == 2 && t == SEQ - 1)
                        out[(size_t)(grow0 + r0 + j) * 512 + d * 256 + col] = hv;
                }
            }
        }
        __syncthreads();   // C (all MFMA reads of A_lds done; all opack writes done)

        // ---- recycle h into recurrent region; publish to next layer ----
        if (L < 2) {
            uint32_t* dst = hbuf + ((size_t)((d * 2 + L) * 4 + (t & 3)) * 512 + grow0) * 256;
            for (int e = tid; e < 4096; e += NT) {
                const uint32_t v = opack[e];
                const int r = e >> 8, c = e & 255;
                Ahi[r * KPS + K1 + c] = (uint16_t)(v >> 16);
                Alo[r * KPS + K1 + c] = (uint16_t)(v & 0xffffu);
                __hip_atomic_store(dst + e, v, __ATOMIC_RELAXED, __HIP_MEMORY_SCOPE_AGENT);
            }
            // release: orders this thread's ring stores before its count increment
            __hip_atomic_fetch_add(&prodf[myFlag], 1u, __ATOMIC_RELEASE, __HIP_MEMORY_SCOPE_AGENT);
        } else {
            for (int e = tid; e < 4096; e += NT) {
                const uint32_t v = opack[e];
                const int r = e >> 8, c = e & 255;
                Ahi[r * KPS + K1 + c] = (uint16_t)(v >> 16);
                Alo[r * KPS + K1 + c] = (uint16_t)(v & 0xffffu);
            }
        }
        // next iteration's barrier A separates these LDS writes from the next GEMM
    }
}

__global__ __launch_bounds__(NT) void rnn_main(const float* __restrict__ x,
                                               const float* __restrict__ fb,
                                               const float* __restrict__ bb,
                                               uint8_t* __restrict__ ws,
                                               float* __restrict__ out)
{
    __shared__ uint16_t Ahi[16 * 584];
    __shared__ uint16_t Alo[16 * 584];
    __shared__ uint32_t opack[4096];
    const int bid = blockIdx.x;
    const int l = bid >> 6;          // layers on same XCD per chain (64 % 8 == 0)
    const int d = (bid >> 5) & 1;
    const int i = bid & 31;
    const float* bias = d ? bb : fb;
    if (l == 0)      run_block<0>(x, bias, ws, out, d, i, Ahi, Alo, opack);
    else if (l == 1) run_block<1>(x, bias, ws, out, d, i, Ahi, Alo, opack);
    else             run_block<2>(x, bias, ws, out, d, i, Ahi, Alo, opack);
}

extern "C" void kernel_launch(void* const* d_in, const int* in_sizes, int n_in,
                              void* d_out, int out_size, void* d_ws, size_t ws_size,
                              hipStream_t stream)
{
    (void)in_sizes; (void)n_in; (void)out_size; (void)ws_size;
    const float* x      = (const float*)d_in[0];
    const float* fW_ih0 = (const float*)d_in[1];
    const float* fW_ih  = (const float*)d_in[2];
    const float* fW_hh  = (const float*)d_in[3];
    const float* fb     = (const float*)d_in[4];
    const float* bW_ih0 = (const float*)d_in[5];
    const float* bW_ih  = (const float*)d_in[6];
    const float* bW_hh  = (const float*)d_in[7];
    const float* bb     = (const float*)d_in[8];
    uint8_t* ws = (uint8_t*)d_ws;

    rnn_prep<<<401, 256, 0, stream>>>(fW_ih0, fW_ih, fW_hh, bW_ih0, bW_ih, bW_hh, ws);
    rnn_main<<<192, NT, 0, stream>>>(x, fb, bb, ws, (float*)d_out);
}

// Round 2
// 8362.682 us; speedup vs baseline: 1.4737x; 1.4737x over previous
//
#include <hip/hip_runtime.h>
#include <cstdint>
#include <cstddef>

// Bidirectional 3-layer tanh RNN, S=512 B=512 D=300 H=256.
// 192 persistent blocks = 2 dirs x 3 layers x 32 batch-tiles (16 rows).
// R2: register-resident weights, single flag RMW per block per step,
//     ring data loaded direct-to-fragment (no LDS round trip), 2 barriers/step.
// GEMM: fp16 2-term split (A = hi+lo), W fp16, mfma_f32_16x16x32_f16, fp32 acc.

#define SEQ    512
#define BATCH  512
#define DIN    300
#define HDIM   256
#define NT     512   // 8 waves

typedef _Float16 f16x8 __attribute__((ext_vector_type(8)));
typedef float    f32x4 __attribute__((ext_vector_type(4)));

// ---- workspace layout (bytes) ----
// L0 K-space: x in [0,320) (zeros at [300,320)), h_rec in [320,576). KT=18.
// L1/L2: input [0,256), h_rec [256,512). KT=16.
#define WD_STRIDE 819200
#define W_L1_OFF  294912
#define W_L2_OFF  557056
#define HOFF      1638400                 // u32 ring [2 dir][2 layer][4 slot][512 row][256 col]
#define FOFF      (HOFF + 8388608)        // prodf u32[128], consf u32[128]

static __device__ __forceinline__ uint16_t f16bits(_Float16 h) {
    union { _Float16 h; uint16_t u; } v; v.h = h; return v.u;
}

// ---------------- prep: permute/convert weights to fp16 lane-chunks, zero flags -------------
__global__ void rnn_prep(const float* __restrict__ fW_ih0, const float* __restrict__ fW_ih,
                         const float* __restrict__ fW_hh,  const float* __restrict__ bW_ih0,
                         const float* __restrict__ bW_ih,  const float* __restrict__ bW_hh,
                         uint8_t* __restrict__ ws)
{
    if (blockIdx.x == 400) {            // zero flags
        ((uint32_t*)(ws + FOFF))[threadIdx.x] = 0;
        return;
    }
    const int gid = blockIdx.x * 256 + threadIdx.x;   // 0..102399
    const int d = gid / 51200;
    int r = gid - d * 51200;
    const float* Wih0 = d ? bW_ih0 : fW_ih0;
    const float* Wih  = d ? bW_ih  : fW_ih;
    const float* Whh  = d ? bW_hh  : fW_hh;
    int l, lr, Ktiles; size_t base;
    if (r < 18432)      { l = 0; lr = r;         Ktiles = 18; base = (size_t)d*WD_STRIDE; }
    else if (r < 34816) { l = 1; lr = r - 18432; Ktiles = 16; base = (size_t)d*WD_STRIDE + W_L1_OFF; }
    else                { l = 2; lr = r - 34816; Ktiles = 16; base = (size_t)d*WD_STRIDE + W_L2_OFF; }
    const int ck = lr >> 6, lane = lr & 63;
    const int wc = ck / Ktiles, kt = ck - wc * Ktiles;
    const int col = wc * 16 + (lane & 15);
    const int k0  = kt * 32 + (lane >> 4) * 8;
    _Float16 vals[8];
    #pragma unroll
    for (int e = 0; e < 8; ++e) {
        const int k = k0 + e;
        float v = 0.f;
        if (l == 0) {
            if (k < 300)       v = Wih0[k * 256 + col];          // x region
            else if (k >= 320) v = Whh[(k - 320) * 256 + col];   // h region (k-320 < 256)
            // [300,320) stays 0
        } else {
            if (k < 256) v = Wih[((l - 1) * 256 + k) * 256 + col];
            else         v = Whh[(l * 256 + (k - 256)) * 256 + col];
        }
        vals[e] = (_Float16)v;
    }
    *(f16x8*)(ws + base + ((size_t)ck * 64 + lane) * 16) = *(const f16x8*)vals;
}

// ---------------- main persistent RNN block ----------------
template<int L>
__device__ void run_block(const float* __restrict__ x, const float* __restrict__ bias_base,
                          uint8_t* __restrict__ ws, float* __restrict__ out,
                          int d, int i, uint16_t* Ahi, uint16_t* Alo)
{
    constexpr int KTIN = (L == 0) ? 10 : 8;        // input K tiles of 32
    constexpr int KT   = KTIN + 8;                 // + recurrent tiles
    constexpr int K1   = (L == 0) ? 320 : 256;     // recurrent region offset in K
    constexpr int KPS  = K1 + 264;                 // padded LDS row stride (elements)
    constexpr size_t WOFFL = (L == 0) ? 0 : ((L == 1) ? (size_t)W_L1_OFF : (size_t)W_L2_OFF);

    const int tid  = threadIdx.x;
    const int lane = tid & 63;
    const int w    = tid >> 6;                     // 8 waves, 2 coltiles each

    const _Float16* __restrict__ Wg = (const _Float16*)(ws + (size_t)d * WD_STRIDE + WOFFL);
    uint32_t* hbuf  = (uint32_t*)(ws + HOFF);
    uint32_t* prodf = (uint32_t*)(ws + FOFF);
    uint32_t* consf = prodf + 128;

    const int grow0 = i * 16;
    const float* bias = bias_base + L * HDIM;
    float bv[2];
    #pragma unroll
    for (int c = 0; c < 2; ++c) bv[c] = bias[(w * 2 + c) * 16 + (lane & 15)];

    // ---- preload weights into registers (held across whole kernel) ----
    f16x8 wv[2][KT];
    #pragma unroll
    for (int c = 0; c < 2; ++c) {
        #pragma unroll
        for (int kt = 0; kt < KT; ++kt)
            wv[c][kt] = *(const f16x8*)(Wg + (((size_t)(w * 2 + c) * KT + kt) * 64 + lane) * 8);
    }

    // ---- zero LDS (covers x pad and initial h=0) ----
    for (int idx = tid; idx < 16 * KPS; idx += NT) { Ahi[idx] = 0; Alo[idx] = 0; }
    __syncthreads();

    const uint16_t* ArH = Ahi + (lane & 15) * KPS + ((lane >> 4) << 3);
    const uint16_t* ArL = Alo + (lane & 15) * KPS + ((lane >> 4) << 3);

    const int upFlag = (d * 2 + (L - 1)) * 32 + i;   // valid when L>0
    const int myFlag = (d * 2 + L) * 32 + i;         // valid when L<2

    // ---- prologue: stage x(step 0) for L0 ----
    if constexpr (L == 0) {
        const int ts = d ? (SEQ - 1) : 0;
        const float* xs = x + ((size_t)ts * BATCH + grow0) * DIN;
        for (int p = tid; p < 2400; p += NT) {
            const int r = p / 150, c2 = (p - r * 150) * 2;
            const float2 v = *(const float2*)(xs + r * DIN + c2);
            const _Float16 h0 = (_Float16)v.x, h1 = (_Float16)v.y;
            const _Float16 g0 = (_Float16)(v.x - (float)h0), g1 = (_Float16)(v.y - (float)h1);
            *(uint32_t*)&Ahi[r * KPS + c2] = (uint32_t)f16bits(h0) | ((uint32_t)f16bits(h1) << 16);
            *(uint32_t*)&Alo[r * KPS + c2] = (uint32_t)f16bits(g0) | ((uint32_t)f16bits(g1) << 16);
        }
    }
    __syncthreads();

    uint32_t seenP = 0, seenC = 0;   // tid0's cached flag values (monotonic)

    for (int t = 0; t < SEQ; ++t) {
        // ---- tid0: poll availability/backpressure (others park at barrier A) ----
        if (tid == 0) {
            if (L > 0 && seenP < (uint32_t)(t + 1)) {
                do {
                    seenP = __hip_atomic_load(&prodf[upFlag], __ATOMIC_RELAXED, __HIP_MEMORY_SCOPE_AGENT);
                    if (seenP >= (uint32_t)(t + 1)) break;
                    __builtin_amdgcn_s_sleep(1);
                } while (true);
            }
            if (L < 2 && t >= 4 && seenC < (uint32_t)(t - 3)) {
                do {
                    seenC = __hip_atomic_load(&consf[myFlag], __ATOMIC_RELAXED, __HIP_MEMORY_SCOPE_AGENT);
                    if (seenC >= (uint32_t)(t - 3)) break;
                    __builtin_amdgcn_s_sleep(1);
                } while (true);
            }
        }
        __syncthreads();   // A: prev act writes drained (vmcnt 0 per thread); flags satisfied

        // ---- tid0: post previous step's flags (stores of t-1 are globally done at A) ----
        if (tid == 0 && t > 0) {
            if (L < 2) __hip_atomic_fetch_add(&prodf[myFlag], 1u, __ATOMIC_RELEASE, __HIP_MEMORY_SCOPE_AGENT);
            if (L > 0) __hip_atomic_fetch_add(&consf[upFlag], 1u, __ATOMIC_RELAXED, __HIP_MEMORY_SCOPE_AGENT);
        }

        // ---- GEMM ----
        f32x4 acc[2][2] = {{{0.f,0.f,0.f,0.f},{0.f,0.f,0.f,0.f}},
                           {{0.f,0.f,0.f,0.f},{0.f,0.f,0.f,0.f}}};

        if constexpr (L > 0) {
            // issue ring loads for this step (direct-to-fragment, bypass L1/L2)
            const uint32_t* src = hbuf
                + ((size_t)((d * 2 + (L - 1)) * 4 + (t & 3)) * 512 + grow0 + (lane & 15)) * 256
                + ((lane >> 4) << 3);
            uint32_t q[8][8];
            #pragma unroll
            for (int kt = 0; kt < 8; ++kt) {
                #pragma unroll
                for (int e = 0; e < 8; ++e)
                    q[kt][e] = __hip_atomic_load(src + kt * 32 + e, __ATOMIC_RELAXED, __HIP_MEMORY_SCOPE_AGENT);
            }
            // recurrent phase (LDS) while ring loads are in flight
            #pragma unroll
            for (int kt = 0; kt < 8; ++kt) {
                const f16x8 ah = *(const f16x8*)(ArH + K1 + kt * 32);
                const f16x8 al = *(const f16x8*)(ArL + K1 + kt * 32);
                #pragma unroll
                for (int c = 0; c < 2; ++c) {
                    acc[c][0] = __builtin_amdgcn_mfma_f32_16x16x32_f16(ah, wv[c][8 + kt], acc[c][0], 0, 0, 0);
                    acc[c][1] = __builtin_amdgcn_mfma_f32_16x16x32_f16(al, wv[c][8 + kt], acc[c][1], 0, 0, 0);
                }
            }
            // input phase: unpack packed u32 -> hi/lo f16x8 via v_perm, MFMA
            #pragma unroll
            for (int kt = 0; kt < 8; ++kt) {
                union { f16x8 f; uint32_t u[4]; } fh, fl;
                #pragma unroll
                for (int p2 = 0; p2 < 4; ++p2) {
                    fh.u[p2] = __builtin_amdgcn_perm(q[kt][2*p2+1], q[kt][2*p2], 0x07060302u);
                    fl.u[p2] = __builtin_amdgcn_perm(q[kt][2*p2+1], q[kt][2*p2], 0x05040100u);
                }
                #pragma unroll
                for (int c = 0; c < 2; ++c) {
                    acc[c][0] = __builtin_amdgcn_mfma_f32_16x16x32_f16(fh.f, wv[c][kt], acc[c][0], 0, 0, 0);
                    acc[c][1] = __builtin_amdgcn_mfma_f32_16x16x32_f16(fl.f, wv[c][kt], acc[c][1], 0, 0, 0);
                }
            }
        } else {
            // L0: recurrent phase then x phase, all from LDS
            #pragma unroll
            for (int kt = 0; kt < 8; ++kt) {
                const f16x8 ah = *(const f16x8*)(ArH + K1 + kt * 32);
                const f16x8 al = *(const f16x8*)(ArL + K1 + kt * 32);
                #pragma unroll
                for (int c = 0; c < 2; ++c) {
                    acc[c][0] = __builtin_amdgcn_mfma_f32_16x16x32_f16(ah, wv[c][10 + kt], acc[c][0], 0, 0, 0);
                    acc[c][1] = __builtin_amdgcn_mfma_f32_16x16x32_f16(al, wv[c][10 + kt], acc[c][1], 0, 0, 0);
                }
            }
            #pragma unroll
            for (int kt = 0; kt < 10; ++kt) {
                const f16x8 ah = *(const f16x8*)(ArH + kt * 32);
                const f16x8 al = *(const f16x8*)(ArL + kt * 32);
                #pragma unroll
                for (int c = 0; c < 2; ++c) {
                    acc[c][0] = __builtin_amdgcn_mfma_f32_16x16x32_f16(ah, wv[c][kt], acc[c][0], 0, 0, 0);
                    acc[c][1] = __builtin_amdgcn_mfma_f32_16x16x32_f16(al, wv[c][kt], acc[c][1], 0, 0, 0);
                }
            }
        }

        // ---- L0: issue x(t+1) global loads now (latency hides under act window) ----
        float2 xv[5];
        if constexpr (L == 0) {
            if (t < SEQ - 1) {
                const int ts = d ? (SEQ - 2 - t) : (t + 1);
                const float* xs = x + ((size_t)ts * BATCH + grow0) * DIN;
                #pragma unroll
                for (int b = 0; b < 5; ++b) {
                    const int p = tid + b * NT;
                    if (p < 2400) {
                        const int r = p / 150, c2 = (p - r * 150) * 2;
                        xv[b] = *(const float2*)(xs + r * DIN + c2);
                    }
                }
            }
        }
        __syncthreads();   // B: all LDS fragment reads (and ring reads) of step t done

        // ---- activation + recycle + publish ----
        {
            const int r0 = (lane >> 4) << 2;       // C/D: col = lane&15, row = (lane>>4)*4 + j
            uint32_t* slotw = hbuf + (size_t)((d * 2 + L) * 4 + (t & 3)) * 512 * 256;
            #pragma unroll
            for (int c = 0; c < 2; ++c) {
                const int col = (w * 2 + c) * 16 + (lane & 15);
                #pragma unroll
                for (int j = 0; j < 4; ++j) {
                    float z = acc[c][0][j] + acc[c][1][j] + bv[c];
                    z = fminf(fmaxf(z, -15.f), 15.f);
                    const float ex = __expf(2.f * z);
                    const float hv = (ex - 1.f) / (ex + 1.f);
                    const _Float16 hh = (_Float16)hv;
                    const _Float16 hl = (_Float16)(hv - (float)hh);
                    const int rr = r0 + j;
                    Ahi[rr * KPS + K1 + col] = f16bits(hh);
                    Alo[rr * KPS + K1 + col] = f16bits(hl);
                    if (L < 2)
                        __hip_atomic_store(slotw + (size_t)(grow0 + rr) * 256 + col,
                                           ((uint32_t)f16bits(hh) << 16) | (uint32_t)f16bits(hl),
                                           __ATOMIC_RELAXED, __HIP_MEMORY_SCOPE_AGENT);
                    if (L == 2 && t == SEQ - 1)
                        out[(size_t)(grow0 + rr) * 512 + d * 256 + col] = hv;
                }
            }
        }

        // ---- L0: convert + write staged x(t+1) into LDS input region ----
        if constexpr (L == 0) {
            if (t < SEQ - 1) {
                #pragma unroll
                for (int b = 0; b < 5; ++b) {
                    const int p = tid + b * NT;
                    if (p < 2400) {
                        const int r = p / 150, c2 = (p - r * 150) * 2;
                        const float2 v = xv[b];
                        const _Float16 h0 = (_Float16)v.x, h1 = (_Float16)v.y;
                        const _Float16 g0 = (_Float16)(v.x - (float)h0), g1 = (_Float16)(v.y - (float)h1);
                        *(uint32_t*)&Ahi[r * KPS + c2] = (uint32_t)f16bits(h0) | ((uint32_t)f16bits(h1) << 16);
                        *(uint32_t*)&Alo[r * KPS + c2] = (uint32_t)f16bits(g0) | ((uint32_t)f16bits(g1) << 16);
                    }
                }
            }
        }
        // next iteration's barrier A orders these LDS/global writes before the next GEMM
    }

    // ---- final flag posts ----
    __syncthreads();
    if (tid == 0 && L < 2)
        __hip_atomic_fetch_add(&prodf[myFlag], 1u, __ATOMIC_RELEASE, __HIP_MEMORY_SCOPE_AGENT);
}

__global__ __launch_bounds__(NT, 2) void rnn_main(const float* __restrict__ x,
                                                  const float* __restrict__ fb,
                                                  const float* __restrict__ bb,
                                                  uint8_t* __restrict__ ws,
                                                  float* __restrict__ out)
{
    __shared__ uint16_t Ahi[16 * 584];
    __shared__ uint16_t Alo[16 * 584];
    const int bid = blockIdx.x;
    const int l = bid >> 6;          // chain layers share XCD (64 % 8 == 0)
    const int d = (bid >> 5) & 1;
    const int i = bid & 31;
    const float* bias = d ? bb : fb;
    if (l == 0)      run_block<0>(x, bias, ws, out, d, i, Ahi, Alo);
    else if (l == 1) run_block<1>(x, bias, ws, out, d, i, Ahi, Alo);
    else             run_block<2>(x, bias, ws, out, d, i, Ahi, Alo);
}

extern "C" void kernel_launch(void* const* d_in, const int* in_sizes, int n_in,
                              void* d_out, int out_size, void* d_ws, size_t ws_size,
                              hipStream_t stream)
{
    (void)in_sizes; (void)n_in; (void)out_size; (void)ws_size;
    const float* x      = (const float*)d_in[0];
    const float* fW_ih0 = (const float*)d_in[1];
    const float* fW_ih  = (const float*)d_in[2];
    const float* fW_hh  = (const float*)d_in[3];
    const float* fb     = (const float*)d_in[4];
    const float* bW_ih0 = (const float*)d_in[5];
    const float* bW_ih  = (const float*)d_in[6];
    const float* bW_hh  = (const float*)d_in[7];
    const float* bb     = (const float*)d_in[8];
    uint8_t* ws = (uint8_t*)d_ws;

    rnn_prep<<<401, 256, 0, stream>>>(fW_ih0, fW_ih, fW_hh, bW_ih0, bW_ih, bW_hh, ws);
    rnn_main<<<192, NT, 0, stream>>>(x, fb, bb, ws, (float*)d_out);
}

// Round 3
// 2226.516 us; speedup vs baseline: 5.5350x; 3.7560x over previous
//
#include <hip/hip_runtime.h>
#include <cstdint>
#include <cstddef>

// Bidirectional 3-layer tanh RNN, S=512 B=512 D=300 H=256.
// R3: layer-sequential passes, ZERO cross-block sync.
//   prep               : permute weights to f16 MFMA fragment layout
//   per chunk g:
//     gemm0(g)         : Zin0 = x @ W_ih0 (both dirs), full-GPU GEMM
//     rec<0>(g)        : h0 = tanh(Zin0 + h0@Whh0 + b0); emits Zin1 = h0@Wih1 (lagged)
//     rec<1>(g)        : h1 = tanh(Zin1 + h1@Whh1 + b1); emits Zin2 = h1@Wih2
//     rec<2>(g)        : h2 = tanh(Zin2 + h2@Whh2 + b2); writes out at t=511
// Rec blocks: 64 = 2 dirs x 32 batch-tiles(16 rows); W in registers; h in LDS
// double-buffer; one __syncthreads per step; NO atomics/flags anywhere.
// Chunk size CH adapts to ws_size (Zin ring buffers = 3 x 0.5*CH MB).

#define SEQ   512
#define BATCH 512
#define DIN   300
#define HDIM  256
#define NT    512   // 8 waves

typedef _Float16 f16x8 __attribute__((ext_vector_type(8)));
typedef float    f32x4 __attribute__((ext_vector_type(4)));

// ---- ws layout ----
// f16-element offsets for weight fragments:
#define WIH0_E 0         // [2 dir][16 ct][10 kt][64 lane][8]  (K=320, zeros at k in [300,320))
#define WHH_E  163840    // [2][3 layer][16 ct][8 kt][64][8]
#define WIHN_E 557056    // [2][2 (->layer1,2)][16 ct][8 kt][64][8]
// byte offsets:
#define HC_BYTE 1638400  // h carry u16 [2 dir][3 layer][512 b][256 h]
#define ZB_BYTE 3211264  // 3 Zin ring buffers f16, each [2 dir][CH][512 b][256 h]

static __device__ __forceinline__ uint16_t f16bits(_Float16 h) {
    union { _Float16 h; uint16_t u; } v; v.h = h; return v.u;
}
static __device__ __forceinline__ float b2f(uint16_t u) {
    union { uint16_t u; _Float16 h; } v; v.u = u; return (float)v.h;
}

// ---------------- prep: weights -> f16 fragment layout ----------------
__global__ void rnn_prep(const float* __restrict__ fW_ih0, const float* __restrict__ fW_ih,
                         const float* __restrict__ fW_hh,  const float* __restrict__ bW_ih0,
                         const float* __restrict__ bW_ih,  const float* __restrict__ bW_hh,
                         _Float16* __restrict__ wf)
{
    const int gid = blockIdx.x * 256 + threadIdx.x;   // 0..102399
    const int d = gid / 51200;
    const int r = gid - d * 51200;
    const int lane = r & 63;
    const float* Wih0 = d ? bW_ih0 : fW_ih0;
    const float* Wih  = d ? bW_ih  : fW_ih;
    const float* Whh  = d ? bW_hh  : fW_hh;
    _Float16 vals[8];
    size_t dstE;
    if (r < 10240) {                       // W_ih0 frags, K=320 padded
        const int ck = r >> 6, ct = ck / 10, kt = ck - ct * 10;
        const int col = ct * 16 + (lane & 15);
        const int k0  = kt * 32 + (lane >> 4) * 8;
        #pragma unroll
        for (int e = 0; e < 8; ++e) {
            const int k = k0 + e;
            vals[e] = (k < 300) ? (_Float16)Wih0[(size_t)k * 256 + col] : (_Float16)0.f;
        }
        dstE = (size_t)WIH0_E + (size_t)d * 81920 + (size_t)r * 8;
    } else if (r < 34816) {                // W_hh frags
        const int rr = r - 10240, l = rr / 8192, r2 = rr - l * 8192;
        const int ck = r2 >> 6, ct = ck >> 3, kt = ck & 7;
        const int col = ct * 16 + (lane & 15);
        const int k0  = kt * 32 + (lane >> 4) * 8;
        #pragma unroll
        for (int e = 0; e < 8; ++e)
            vals[e] = (_Float16)Whh[((size_t)(l * 256 + k0 + e)) * 256 + col];
        dstE = (size_t)WHH_E + (size_t)(d * 3 + l) * 65536 + (size_t)r2 * 8;
    } else {                               // W_ih layers 1,2 frags
        const int rr = r - 34816, ln = rr / 8192, r2 = rr - ln * 8192;
        const int ck = r2 >> 6, ct = ck >> 3, kt = ck & 7;
        const int col = ct * 16 + (lane & 15);
        const int k0  = kt * 32 + (lane >> 4) * 8;
        #pragma unroll
        for (int e = 0; e < 8; ++e)
            vals[e] = (_Float16)Wih[((size_t)(ln * 256 + k0 + e)) * 256 + col];
        dstE = (size_t)WIHN_E + (size_t)(d * 2 + ln) * 65536 + (size_t)r2 * 8;
    }
    *(f16x8*)(wf + dstE) = *(const f16x8*)vals;
}

// ---------------- gemm0: Zin0 = x @ W_ih0 (both dirs) ----------------
__global__ __launch_bounds__(NT) void rnn_gemm0(const float* __restrict__ x,
                                                const _Float16* __restrict__ wih0,
                                                uint16_t* __restrict__ zin0,
                                                int CH, int g)
{
    __shared__ uint16_t Xl[128 * 328];     // 128 rows x K=320 (+8 pad), f16
    const int tid = threadIdx.x, lane = tid & 63, w = tid >> 6;
    const int rowbase = blockIdx.x * 128;
    const int slab = rowbase >> 9;         // (d*CH + tmod)
    const int dd = (slab >= CH) ? 1 : 0;
    const int tmod = slab - dd * CH;
    const int t = g * CH + tmod;
    const int s = dd ? (SEQ - 1 - t) : t;
    const int b0 = rowbase & 511;
    const _Float16* W = wih0 + (size_t)dd * 81920;

    f16x8 wv[2][10];
    #pragma unroll
    for (int c = 0; c < 2; ++c)
        #pragma unroll
        for (int kt = 0; kt < 10; ++kt)
            wv[c][kt] = *(const f16x8*)(W + (((size_t)(w * 2 + c) * 10 + kt) * 64 + lane) * 8);

    for (int p = tid; p < 19200; p += NT) {            // 128 rows x 150 float2
        const int r = p / 150, c2 = (p - r * 150) * 2;
        const float2 v = *(const float2*)(x + (size_t)(s * BATCH + b0 + r) * DIN + c2);
        const uint32_t pk = (uint32_t)f16bits((_Float16)v.x)
                          | ((uint32_t)f16bits((_Float16)v.y) << 16);
        *(uint32_t*)&Xl[r * 328 + c2] = pk;
    }
    for (int p = tid; p < 1280; p += NT) {             // zero k in [300,320)
        const int r = p / 10, c2 = 300 + (p - r * 10) * 2;
        *(uint32_t*)&Xl[r * 328 + c2] = 0;
    }
    __syncthreads();

    f32x4 acc[8][2] = {};
    #pragma unroll
    for (int kt = 0; kt < 10; ++kt) {
        #pragma unroll
        for (int m = 0; m < 8; ++m) {
            const f16x8 a = *(const f16x8*)&Xl[(m * 16 + (lane & 15)) * 328 + kt * 32 + (lane >> 4) * 8];
            acc[m][0] = __builtin_amdgcn_mfma_f32_16x16x32_f16(a, wv[0][kt], acc[m][0], 0, 0, 0);
            acc[m][1] = __builtin_amdgcn_mfma_f32_16x16x32_f16(a, wv[1][kt], acc[m][1], 0, 0, 0);
        }
    }
    #pragma unroll
    for (int m = 0; m < 8; ++m)
        #pragma unroll
        for (int c = 0; c < 2; ++c)
            #pragma unroll
            for (int j = 0; j < 4; ++j) {
                const int row = rowbase + m * 16 + (lane >> 4) * 4 + j;
                const int col = (w * 2 + c) * 16 + (lane & 15);
                zin0[(size_t)row * 256 + col] = f16bits((_Float16)acc[m][c][j]);
            }
}

// ---------------- rec<L>: recurrent pass over one chunk ----------------
template<int L>
__global__ __launch_bounds__(NT) void rnn_rec(const _Float16* __restrict__ whh_all,
                                              const _Float16* __restrict__ wihn_all,
                                              const uint16_t* __restrict__ zsrc,
                                              uint16_t* __restrict__ zdst,
                                              uint16_t* __restrict__ hcarry,
                                              const float* __restrict__ fb,
                                              const float* __restrict__ bb,
                                              float* __restrict__ out,
                                              int CH, int g)
{
    __shared__ uint16_t Hb[2 * 16 * 264];              // double-buffered h, KPS=264
    const int tid = threadIdx.x, lane = tid & 63, w = tid >> 6;
    const int d = blockIdx.x >> 5, i = blockIdx.x & 31;
    const int grow0 = i * 16;
    const int ct0 = w * 2;
    const int colw = lane & 15;
    const int rq = lane >> 4;

    const _Float16* whh = whh_all + (size_t)(d * 3 + L) * 65536;
    f16x8 wv_hh[2][8];
    #pragma unroll
    for (int c = 0; c < 2; ++c)
        #pragma unroll
        for (int kt = 0; kt < 8; ++kt)
            wv_hh[c][kt] = *(const f16x8*)(whh + (((size_t)(ct0 + c) * 8 + kt) * 64 + lane) * 8);
    f16x8 wv_nx[2][8];
    if constexpr (L < 2) {
        const _Float16* wnx = wihn_all + (size_t)(d * 2 + L) * 65536;
        #pragma unroll
        for (int c = 0; c < 2; ++c)
            #pragma unroll
            for (int kt = 0; kt < 8; ++kt)
                wv_nx[c][kt] = *(const f16x8*)(wnx + (((size_t)(ct0 + c) * 8 + kt) * 64 + lane) * 8);
    }

    const float* bias = (d ? bb : fb) + L * HDIM;
    float bv[2];
    #pragma unroll
    for (int c = 0; c < 2; ++c) bv[c] = bias[(ct0 + c) * 16 + colw];

    for (int p = tid; p < 4224; p += NT) ((uint32_t*)Hb)[p] = 0;
    __syncthreads();
    if (g > 0) {                                       // load h carry into buffer 1
        const uint16_t* hc = hcarry + (size_t)(d * 3 + L) * 131072;
        const uint4 v = *(const uint4*)(hc + ((size_t)(grow0 + (tid >> 5)) * 256 + (tid & 31) * 8));
        *(uint4*)&Hb[4224 + (tid >> 5) * 264 + (tid & 31) * 8] = v;
    }
    __syncthreads();

    uint16_t zcur[8];
    #pragma unroll
    for (int q = 0; q < 8; ++q) {
        const int c = q >> 2, j = q & 3;
        zcur[q] = zsrc[((size_t)(d * CH) * 512 + grow0 + rq * 4 + j) * 256 + (ct0 + c) * 16 + colw];
    }

    const int tbase = g * CH;
    for (int k = 0; k < CH; ++k) {
        const int t = tbase + k;
        const int cur = t & 1, prv = cur ^ 1;

        uint16_t znx[8];                                // prefetch Zin(t+1)
        const int km = (k + 1 < CH) ? (k + 1) : k;
        #pragma unroll
        for (int q = 0; q < 8; ++q) {
            const int c = q >> 2, j = q & 3;
            znx[q] = zsrc[((size_t)(d * CH + km) * 512 + grow0 + rq * 4 + j) * 256 + (ct0 + c) * 16 + colw];
        }

        f16x8 ah[8];                                    // h(t-1) fragments
        #pragma unroll
        for (int kt = 0; kt < 8; ++kt)
            ah[kt] = *(const f16x8*)&Hb[prv * 4224 + (lane & 15) * 264 + kt * 32 + (lane >> 4) * 8];

        f32x4 ar0 = {}, ar1 = {}, an0 = {}, an1 = {};
        #pragma unroll
        for (int kt = 0; kt < 8; ++kt) {
            ar0 = __builtin_amdgcn_mfma_f32_16x16x32_f16(ah[kt], wv_hh[0][kt], ar0, 0, 0, 0);
            ar1 = __builtin_amdgcn_mfma_f32_16x16x32_f16(ah[kt], wv_hh[1][kt], ar1, 0, 0, 0);
            if constexpr (L < 2) {
                an0 = __builtin_amdgcn_mfma_f32_16x16x32_f16(ah[kt], wv_nx[0][kt], an0, 0, 0, 0);
                an1 = __builtin_amdgcn_mfma_f32_16x16x32_f16(ah[kt], wv_nx[1][kt], an1, 0, 0, 0);
            }
        }

        if constexpr (L < 2) {                          // Zin_next(t-1), lagged emit
            if (k > 0) {
                #pragma unroll
                for (int q = 0; q < 8; ++q) {
                    const int c = q >> 2, j = q & 3;
                    const float v = c ? an1[j] : an0[j];
                    zdst[((size_t)(d * CH + (k - 1)) * 512 + grow0 + rq * 4 + j) * 256 + (ct0 + c) * 16 + colw]
                        = f16bits((_Float16)v);
                }
            }
        }

        #pragma unroll
        for (int q = 0; q < 8; ++q) {                   // activation + LDS h write
            const int c = q >> 2, j = q & 3;
            float z = (c ? ar1[j] : ar0[j]) + b2f(zcur[q]) + bv[c];
            z = fminf(fmaxf(z, -15.f), 15.f);
            const float ex = __expf(2.f * z);
            const float hv = (ex - 1.f) / (ex + 1.f);
            Hb[cur * 4224 + (rq * 4 + j) * 264 + (ct0 + c) * 16 + colw] = f16bits((_Float16)hv);
            if (L == 2 && t == SEQ - 1)
                out[(size_t)(grow0 + rq * 4 + j) * 512 + d * 256 + (ct0 + c) * 16 + colw] = hv;
        }
        #pragma unroll
        for (int q = 0; q < 8; ++q) zcur[q] = znx[q];
        __syncthreads();
    }

    if constexpr (L < 2) {                              // tail: Zin_next(t_last)
        f16x8 ah[8];
        #pragma unroll
        for (int kt = 0; kt < 8; ++kt)
            ah[kt] = *(const f16x8*)&Hb[4224 + (lane & 15) * 264 + kt * 32 + (lane >> 4) * 8];
        f32x4 an0 = {}, an1 = {};
        #pragma unroll
        for (int kt = 0; kt < 8; ++kt) {
            an0 = __builtin_amdgcn_mfma_f32_16x16x32_f16(ah[kt], wv_nx[0][kt], an0, 0, 0, 0);
            an1 = __builtin_amdgcn_mfma_f32_16x16x32_f16(ah[kt], wv_nx[1][kt], an1, 0, 0, 0);
        }
        #pragma unroll
        for (int q = 0; q < 8; ++q) {
            const int c = q >> 2, j = q & 3;
            const float v = c ? an1[j] : an0[j];
            zdst[((size_t)(d * CH + (CH - 1)) * 512 + grow0 + rq * 4 + j) * 256 + (ct0 + c) * 16 + colw]
                = f16bits((_Float16)v);
        }
    }
    {                                                   // h carry out (buffer 1: CH even)
        uint16_t* hc = hcarry + (size_t)(d * 3 + L) * 131072;
        const uint4 v = *(const uint4*)&Hb[4224 + (tid >> 5) * 264 + (tid & 31) * 8];
        *(uint4*)(hc + ((size_t)(grow0 + (tid >> 5)) * 256 + (tid & 31) * 8)) = v;
    }
}

extern "C" void kernel_launch(void* const* d_in, const int* in_sizes, int n_in,
                              void* d_out, int out_size, void* d_ws, size_t ws_size,
                              hipStream_t stream)
{
    (void)in_sizes; (void)n_in; (void)out_size;
    const float* x      = (const float*)d_in[0];
    const float* fW_ih0 = (const float*)d_in[1];
    const float* fW_ih  = (const float*)d_in[2];
    const float* fW_hh  = (const float*)d_in[3];
    const float* fb     = (const float*)d_in[4];
    const float* bW_ih0 = (const float*)d_in[5];
    const float* bW_ih  = (const float*)d_in[6];
    const float* bW_hh  = (const float*)d_in[7];
    const float* bb     = (const float*)d_in[8];
    uint8_t* ws = (uint8_t*)d_ws;

    int CH = 4;                                        // adaptive chunk size
    for (int c = 512; c >= 4; c >>= 1) {
        const size_t need = (size_t)ZB_BYTE + 3ull * 524288ull * (size_t)c;
        if (need <= ws_size) { CH = c; break; }
    }
    const int nch = SEQ / CH;

    _Float16* wf = (_Float16*)ws;
    uint16_t* hcarry = (uint16_t*)(ws + HC_BYTE);
    const size_t ze = (size_t)262144 * CH;             // f16 elems per Zin buffer
    uint16_t* z0 = (uint16_t*)(ws + ZB_BYTE);
    uint16_t* z1 = z0 + ze;
    uint16_t* z2 = z1 + ze;
    const _Float16* whh  = wf + WHH_E;
    const _Float16* wihn = wf + WIHN_E;
    float* out = (float*)d_out;

    rnn_prep<<<400, 256, 0, stream>>>(fW_ih0, fW_ih, fW_hh, bW_ih0, bW_ih, bW_hh, wf);
    for (int g = 0; g < nch; ++g) {
        rnn_gemm0<<<8 * CH, NT, 0, stream>>>(x, wf, z0, CH, g);
        rnn_rec<0><<<64, NT, 0, stream>>>(whh, wihn, z0, z1, hcarry, fb, bb, out, CH, g);
        rnn_rec<1><<<64, NT, 0, stream>>>(whh, wihn, z1, z2, hcarry, fb, bb, out, CH, g);
        rnn_rec<2><<<64, NT, 0, stream>>>(whh, wihn, z2, nullptr, hcarry, fb, bb, out, CH, g);
    }
}

// Round 4
// 1289.949 us; speedup vs baseline: 9.5537x; 1.7260x over previous
//
#include <hip/hip_runtime.h>
#include <cstdint>
#include <cstddef>

// Bidirectional 3-layer tanh RNN, S=512 B=512 D=300 H=256.
// R4: chunk-pipelined layers (slot s: layer l works chunk s-l), 192 blocks/launch,
//     cross-layer sync via kernel-launch boundaries only. Weights pinned in VGPRs
//     (asm keep-alive). Per-step barrier = lgkmcnt(0)+s_barrier (NO vmcnt drain ->
//     z prefetch/stores stay in flight). Fragment-major z layout (8B vector ops).
//     Fast tanh via exp2+rcp.

#define SEQ   512
#define BATCH 512
#define DIN   300
#define HDIM  256
#define NT    512
#define CH    64
#define NCH   (SEQ / CH)    // 8
#define NSLOT (NCH + 2)     // 10

typedef _Float16 f16x8 __attribute__((ext_vector_type(8)));
typedef float    f32x4 __attribute__((ext_vector_type(4)));

// ---- ws layout ----
#define WIH0_E 0            // f16 [2 dir][16ct][10kt][64][8]
#define WHH_E  163840       // f16 [2][3 layer][16ct][8kt][64][8]
#define WIHN_E 557056       // f16 [2][2 (->l1,l2)][16ct][8kt][64][8]
#define HC_BYTE 1638400     // u16 [2 dir][3 layer][512][256]
#define Z_BYTE  3211264     // 3 z buffers, each u16 [2 dir][512 t][ZTILE]
#define ZTILE  131072       // u16 per (d,t) tile, fragment-major
#define ZBUF_E 134217728ull // u16 elems per z buffer (268 MB)

#define KEEP(x) asm volatile("" : "+v"(x))

static __device__ __forceinline__ uint16_t f16bits(_Float16 h) {
    union { _Float16 h; uint16_t u; } v; v.h = h; return v.u;
}

// fragment-major z index: row = T*16 + rq*4 + j, col = ct*16 + colw
// idx = ((T*16+ct)*4+rq)*64 + colw*4 + j

// ---------------- prep: weights -> f16 fragment layout ----------------
__global__ void rnn_prep(const float* __restrict__ fW_ih0, const float* __restrict__ fW_ih,
                         const float* __restrict__ fW_hh,  const float* __restrict__ bW_ih0,
                         const float* __restrict__ bW_ih,  const float* __restrict__ bW_hh,
                         _Float16* __restrict__ wf)
{
    const int gid = blockIdx.x * 256 + threadIdx.x;   // 0..102399
    const int d = gid / 51200;
    const int r = gid - d * 51200;
    const int lane = r & 63;
    const float* Wih0 = d ? bW_ih0 : fW_ih0;
    const float* Wih  = d ? bW_ih  : fW_ih;
    const float* Whh  = d ? bW_hh  : fW_hh;
    _Float16 vals[8];
    size_t dstE;
    if (r < 10240) {                       // W_ih0 frags, K=320 padded
        const int ck = r >> 6, ct = ck / 10, kt = ck - ct * 10;
        const int col = ct * 16 + (lane & 15);
        const int k0  = kt * 32 + (lane >> 4) * 8;
        #pragma unroll
        for (int e = 0; e < 8; ++e) {
            const int k = k0 + e;
            vals[e] = (k < 300) ? (_Float16)Wih0[(size_t)k * 256 + col] : (_Float16)0.f;
        }
        dstE = (size_t)WIH0_E + (size_t)d * 81920 + (size_t)r * 8;
    } else if (r < 34816) {                // W_hh frags
        const int rr = r - 10240, l = rr / 8192, r2 = rr - l * 8192;
        const int ck = r2 >> 6, ct = ck >> 3, kt = ck & 7;
        const int col = ct * 16 + (lane & 15);
        const int k0  = kt * 32 + (lane >> 4) * 8;
        #pragma unroll
        for (int e = 0; e < 8; ++e)
            vals[e] = (_Float16)Whh[((size_t)(l * 256 + k0 + e)) * 256 + col];
        dstE = (size_t)WHH_E + (size_t)(d * 3 + l) * 65536 + (size_t)r2 * 8;
    } else {                               // W_ih layers 1,2 frags
        const int rr = r - 34816, ln = rr / 8192, r2 = rr - ln * 8192;
        const int ck = r2 >> 6, ct = ck >> 3, kt = ck & 7;
        const int col = ct * 16 + (lane & 15);
        const int k0  = kt * 32 + (lane >> 4) * 8;
        #pragma unroll
        for (int e = 0; e < 8; ++e)
            vals[e] = (_Float16)Wih[((size_t)(ln * 256 + k0 + e)) * 256 + col];
        dstE = (size_t)WIHN_E + (size_t)(d * 2 + ln) * 65536 + (size_t)r2 * 8;
    }
    *(f16x8*)(wf + dstE) = *(const f16x8*)vals;
}

// ---------------- gemm0: Zin0 = x @ W_ih0, both dirs per block ----------------
__global__ __launch_bounds__(NT) void rnn_gemm0(const float* __restrict__ x,
                                                const _Float16* __restrict__ wih0,
                                                uint16_t* __restrict__ z0)
{
    __shared__ uint16_t Xl[128 * 328];     // 128 rows x K=320 (+8 pad)
    const int tid = threadIdx.x, lane = tid & 63, w = tid >> 6;
    const int colw = lane & 15, rq = lane >> 4, rq8 = rq * 8;
    const int ct0 = w * 2;
    const int s = blockIdx.x >> 2, rb = blockIdx.x & 3;
    const int b0 = rb * 128;

    for (int p = tid; p < 19200; p += NT) {            // stage x slice (read once)
        const int r = p / 150, c2 = (p - r * 150) * 2;
        const float2 v = *(const float2*)(x + (size_t)(s * BATCH + b0 + r) * DIN + c2);
        *(uint32_t*)&Xl[r * 328 + c2] =
            (uint32_t)f16bits((_Float16)v.x) | ((uint32_t)f16bits((_Float16)v.y) << 16);
    }
    for (int p = tid; p < 1280; p += NT) {             // zero pad k in [300,320)
        const int r = p / 10, c2 = 300 + (p - r * 10) * 2;
        *(uint32_t*)&Xl[r * 328 + c2] = 0;
    }
    __syncthreads();

    #pragma unroll 1
    for (int dd = 0; dd < 2; ++dd) {
        const _Float16* W = wih0 + (size_t)dd * 81920;
        const int t = dd ? (SEQ - 1 - s) : s;
        f16x8 wv[2][10];
        #pragma unroll
        for (int c = 0; c < 2; ++c)
            #pragma unroll
            for (int kt = 0; kt < 10; ++kt)
                wv[c][kt] = *(const f16x8*)(W + (((size_t)(ct0 + c) * 10 + kt) * 64 + lane) * 8);
        f32x4 acc[8][2] = {};
        #pragma unroll
        for (int kt = 0; kt < 10; ++kt)
            #pragma unroll
            for (int m = 0; m < 8; ++m) {
                const f16x8 a = *(const f16x8*)&Xl[(m * 16 + (lane & 15)) * 328 + kt * 32 + rq8];
                acc[m][0] = __builtin_amdgcn_mfma_f32_16x16x32_f16(a, wv[0][kt], acc[m][0], 0, 0, 0);
                acc[m][1] = __builtin_amdgcn_mfma_f32_16x16x32_f16(a, wv[1][kt], acc[m][1], 0, 0, 0);
            }
        uint16_t* zt = z0 + (size_t)(dd * SEQ + t) * ZTILE;
        #pragma unroll
        for (int m = 0; m < 8; ++m)
            #pragma unroll
            for (int c = 0; c < 2; ++c) {
                uint2 sv;
                sv.x = (uint32_t)f16bits((_Float16)acc[m][c][0])
                     | ((uint32_t)f16bits((_Float16)acc[m][c][1]) << 16);
                sv.y = (uint32_t)f16bits((_Float16)acc[m][c][2])
                     | ((uint32_t)f16bits((_Float16)acc[m][c][3]) << 16);
                const int T = rb * 8 + m;
                *(uint2*)(zt + (((T * 16 + ct0 + c) * 4 + rq) * 64 + colw * 4)) = sv;
            }
    }
}

// ---------------- pipelined recurrent kernel ----------------
template<int L>
__device__ __forceinline__ void pipe_run(const _Float16* whh_all, const _Float16* wihn_all,
                                         const uint16_t* zsrc, uint16_t* zdst,
                                         uint16_t* hcarry, const float* fb, const float* bb,
                                         float* out, int d, int i, int cs, uint16_t* Hb)
{
    const int tid = threadIdx.x, lane = tid & 63, w = tid >> 6;
    const int colw = lane & 15, rq = lane >> 4, rq8 = rq * 8;
    const int ct0 = w * 2;
    const int grow0 = i * 16;
    const int tbase = cs * CH;

    // ---- weights -> pinned registers ----
    const _Float16* whh = whh_all + (size_t)(d * 3 + L) * 65536;
    f16x8 wh0[8], wh1[8];
    #pragma unroll
    for (int kt = 0; kt < 8; ++kt) {
        wh0[kt] = *(const f16x8*)(whh + (((size_t)ct0 * 8 + kt) * 64 + lane) * 8);
        wh1[kt] = *(const f16x8*)(whh + (((size_t)(ct0 + 1) * 8 + kt) * 64 + lane) * 8);
    }
    #pragma unroll
    for (int kt = 0; kt < 8; ++kt) { KEEP(wh0[kt]); KEEP(wh1[kt]); }
    f16x8 wn0[8], wn1[8];
    if constexpr (L < 2) {
        const _Float16* wnx = wihn_all + (size_t)(d * 2 + L) * 65536;
        #pragma unroll
        for (int kt = 0; kt < 8; ++kt) {
            wn0[kt] = *(const f16x8*)(wnx + (((size_t)ct0 * 8 + kt) * 64 + lane) * 8);
            wn1[kt] = *(const f16x8*)(wnx + (((size_t)(ct0 + 1) * 8 + kt) * 64 + lane) * 8);
        }
        #pragma unroll
        for (int kt = 0; kt < 8; ++kt) { KEEP(wn0[kt]); KEEP(wn1[kt]); }
    }

    const float* bias = (d ? bb : fb) + L * HDIM;
    const float bv0 = bias[ct0 * 16 + colw];
    const float bv1 = bias[(ct0 + 1) * 16 + colw];

    // ---- init h LDS (zero; carry-in to buffer 1) ----
    for (int p = tid; p < 4224; p += NT) ((uint32_t*)Hb)[p] = 0;
    __syncthreads();
    if (cs > 0) {
        const uint16_t* hc = hcarry + (size_t)(d * 3 + L) * 131072;
        const int row = tid >> 5, c8 = (tid & 31) * 8;
        *(uint4*)&Hb[4224 + row * 264 + c8] = *(const uint4*)(hc + (size_t)(grow0 + row) * 256 + c8);
    }
    __syncthreads();

    // ---- z addressing (fragment-major) ----
    const uint16_t* zsb = zsrc + (size_t)(d * SEQ + tbase) * ZTILE;
    uint16_t* zdb = (L < 2) ? (zdst + (size_t)(d * SEQ + tbase) * ZTILE) : nullptr;
    const int off0 = ((i * 16 + ct0) * 4 + rq) * 64 + colw * 4;
    const int off1 = ((i * 16 + ct0 + 1) * 4 + rq) * 64 + colw * 4;

    uint2 zc0 = *(const uint2*)(zsb + off0);
    uint2 zc1 = *(const uint2*)(zsb + off1);
    uint2 za0 = *(const uint2*)(zsb + ZTILE + off0);
    uint2 za1 = *(const uint2*)(zsb + ZTILE + off1);

    #pragma unroll 1
    for (int k = 0; k < CH; ++k) {
        const int t = tbase + k;
        const int cur = t & 1, prv = cur ^ 1;

        // prefetch z for step k+2 (stays in flight across the barrier)
        const int kp = (k + 2 < CH) ? (k + 2) : (CH - 1);
        uint2 zb0v = *(const uint2*)(zsb + (size_t)kp * ZTILE + off0);
        uint2 zb1v = *(const uint2*)(zsb + (size_t)kp * ZTILE + off1);

        // z + bias for this step (data loaded 2 steps ago)
        float zin[8];
        {
            union { uint2 u; _Float16 h[4]; } a, b;
            a.u = zc0; b.u = zc1;
            #pragma unroll
            for (int j = 0; j < 4; ++j) {
                zin[j]     = (float)a.h[j] + bv0;
                zin[4 + j] = (float)b.h[j] + bv1;
            }
        }

        // GEMM: 4 independent chains over 8 k-tiles
        f32x4 ar0 = {}, ar1 = {}, an0 = {}, an1 = {};
        #pragma unroll
        for (int kt = 0; kt < 8; ++kt) {
            const f16x8 ah = *(const f16x8*)&Hb[prv * 4224 + (lane & 15) * 264 + kt * 32 + rq8];
            ar0 = __builtin_amdgcn_mfma_f32_16x16x32_f16(ah, wh0[kt], ar0, 0, 0, 0);
            ar1 = __builtin_amdgcn_mfma_f32_16x16x32_f16(ah, wh1[kt], ar1, 0, 0, 0);
            if constexpr (L < 2) {
                an0 = __builtin_amdgcn_mfma_f32_16x16x32_f16(ah, wn0[kt], an0, 0, 0, 0);
                an1 = __builtin_amdgcn_mfma_f32_16x16x32_f16(ah, wn1[kt], an1, 0, 0, 0);
            }
        }

        // emit Zin_{l+1}(t-1) = h(t-1) @ Wih_{l+1}  (lagged; k=0 skipped)
        if constexpr (L < 2) {
            if (k > 0) {
                uint2 s0, s1;
                s0.x = (uint32_t)f16bits((_Float16)an0[0]) | ((uint32_t)f16bits((_Float16)an0[1]) << 16);
                s0.y = (uint32_t)f16bits((_Float16)an0[2]) | ((uint32_t)f16bits((_Float16)an0[3]) << 16);
                s1.x = (uint32_t)f16bits((_Float16)an1[0]) | ((uint32_t)f16bits((_Float16)an1[1]) << 16);
                s1.y = (uint32_t)f16bits((_Float16)an1[2]) | ((uint32_t)f16bits((_Float16)an1[3]) << 16);
                *(uint2*)(zdb + (size_t)(k - 1) * ZTILE + off0) = s0;
                *(uint2*)(zdb + (size_t)(k - 1) * ZTILE + off1) = s1;
            }
        }

        // activation: h = tanh(ar + zin) via exp2+rcp (saturates gracefully)
        uint16_t hbits[8];
        float hv[8];
        #pragma unroll
        for (int q = 0; q < 8; ++q) {
            const float z = (q < 4 ? ar0[q] : ar1[q - 4]) + zin[q];
            const float e = __builtin_amdgcn_exp2f(z * 2.885390081777927f);
            const float r = __builtin_amdgcn_rcpf(e + 1.f);
            hv[q] = __builtin_fmaf(-2.f, r, 1.f);
            hbits[q] = f16bits((_Float16)hv[q]);
        }
        #pragma unroll
        for (int q = 0; q < 8; ++q) {
            const int c = q >> 2, j = q & 3;
            Hb[cur * 4224 + (rq * 4 + j) * 264 + (ct0 + c) * 16 + colw] = hbits[q];
        }
        if (L == 2 && t == SEQ - 1) {
            #pragma unroll
            for (int q = 0; q < 8; ++q) {
                const int c = q >> 2, j = q & 3;
                out[(size_t)(grow0 + rq * 4 + j) * 512 + d * 256 + (ct0 + c) * 16 + colw] = hv[q];
            }
        }

        zc0 = za0; zc1 = za1; za0 = zb0v; za1 = zb1v;

        // barrier WITHOUT vmcnt drain: only LDS ops must settle
        __builtin_amdgcn_sched_barrier(0);
        asm volatile("s_waitcnt lgkmcnt(0)" ::: "memory");
        __builtin_amdgcn_s_barrier();
        __builtin_amdgcn_sched_barrier(0);
    }

    // tail: Zin_{l+1}(last t of chunk) from final h (buffer 1)
    if constexpr (L < 2) {
        f32x4 an0 = {}, an1 = {};
        #pragma unroll
        for (int kt = 0; kt < 8; ++kt) {
            const f16x8 ah = *(const f16x8*)&Hb[4224 + (lane & 15) * 264 + kt * 32 + rq8];
            an0 = __builtin_amdgcn_mfma_f32_16x16x32_f16(ah, wn0[kt], an0, 0, 0, 0);
            an1 = __builtin_amdgcn_mfma_f32_16x16x32_f16(ah, wn1[kt], an1, 0, 0, 0);
        }
        uint2 s0, s1;
        s0.x = (uint32_t)f16bits((_Float16)an0[0]) | ((uint32_t)f16bits((_Float16)an0[1]) << 16);
        s0.y = (uint32_t)f16bits((_Float16)an0[2]) | ((uint32_t)f16bits((_Float16)an0[3]) << 16);
        s1.x = (uint32_t)f16bits((_Float16)an1[0]) | ((uint32_t)f16bits((_Float16)an1[1]) << 16);
        s1.y = (uint32_t)f16bits((_Float16)an1[2]) | ((uint32_t)f16bits((_Float16)an1[3]) << 16);
        *(uint2*)(zdb + (size_t)(CH - 1) * ZTILE + off0) = s0;
        *(uint2*)(zdb + (size_t)(CH - 1) * ZTILE + off1) = s1;
    }
    // h carry out (final h is in buffer 1; CH even)
    {
        uint16_t* hc = hcarry + (size_t)(d * 3 + L) * 131072;
        const int row = tid >> 5, c8 = (tid & 31) * 8;
        *(uint4*)(hc + (size_t)(grow0 + row) * 256 + c8) = *(const uint4*)&Hb[4224 + row * 264 + c8];
    }
}

__global__ __launch_bounds__(NT, 2) void rnn_pipe(const _Float16* whh_all,
                                                  const _Float16* wihn_all,
                                                  uint16_t* z0, uint16_t* z1, uint16_t* z2,
                                                  uint16_t* hcarry,
                                                  const float* fb, const float* bb,
                                                  float* out, int slot)
{
    __shared__ uint16_t Hb[2 * 16 * 264];
    const int l = blockIdx.x >> 6, sub = blockIdx.x & 63;
    const int d = sub >> 5, i = sub & 31;
    const int cs = slot - l;
    if (cs < 0 || cs >= NCH) return;
    if (l == 0)      pipe_run<0>(whh_all, wihn_all, z0, z1, hcarry, fb, bb, out, d, i, cs, Hb);
    else if (l == 1) pipe_run<1>(whh_all, wihn_all, z1, z2, hcarry, fb, bb, out, d, i, cs, Hb);
    else             pipe_run<2>(whh_all, wihn_all, z2, nullptr, hcarry, fb, bb, out, d, i, cs, Hb);
}

extern "C" void kernel_launch(void* const* d_in, const int* in_sizes, int n_in,
                              void* d_out, int out_size, void* d_ws, size_t ws_size,
                              hipStream_t stream)
{
    (void)in_sizes; (void)n_in; (void)out_size; (void)ws_size;
    const float* x      = (const float*)d_in[0];
    const float* fW_ih0 = (const float*)d_in[1];
    const float* fW_ih  = (const float*)d_in[2];
    const float* fW_hh  = (const float*)d_in[3];
    const float* fb     = (const float*)d_in[4];
    const float* bW_ih0 = (const float*)d_in[5];
    const float* bW_ih  = (const float*)d_in[6];
    const float* bW_hh  = (const float*)d_in[7];
    const float* bb     = (const float*)d_in[8];
    uint8_t* ws = (uint8_t*)d_ws;

    _Float16* wf     = (_Float16*)ws;
    uint16_t* hcarry = (uint16_t*)(ws + HC_BYTE);
    uint16_t* z0     = (uint16_t*)(ws + Z_BYTE);
    uint16_t* z1     = z0 + ZBUF_E;
    uint16_t* z2     = z1 + ZBUF_E;
    const _Float16* whh  = wf + WHH_E;
    const _Float16* wihn = wf + WIHN_E;
    float* out = (float*)d_out;

    rnn_prep<<<400, 256, 0, stream>>>(fW_ih0, fW_ih, fW_hh, bW_ih0, bW_ih, bW_hh, wf);
    rnn_gemm0<<<2048, NT, 0, stream>>>(x, wf, z0);
    for (int s = 0; s < NSLOT; ++s)
        rnn_pipe<<<192, NT, 0, stream>>>(whh, wihn, z0, z1, z2, hcarry, fb, bb, out, s);
}